// Round 3
// baseline (419.573 us; speedup 1.0000x reference)
//
#include <hip/hip_runtime.h>
#include <stdint.h>

// ---------------------------------------------------------------------------
// QuantizedLinear via int8 MFMA: y[m,n] = s_x*s_w * (xq @ wq^T)[m,n] + bias[n]
// W int8 exact; x quantized at 6/127 (clamp +-6). int32 accum exact.
// GEMM: m97 structure, 128x128 tile, BK=64 i8, mfma_i32_16x16x64_i8.
// R3: XOR-swizzled LDS chunk layout -> fragment ds_read_b128 goes from
//     8-way bank conflict (2.94x) to 2-way (free). Swizzle is applied on the
//     GLOBAL source address at staging (global_load_lds store order is fixed
//     at base+lane*16, but per-lane source is free), and on the LDS read
//     address at fragment load. Data identical -> bit-identical result.
// ---------------------------------------------------------------------------

#define M_TOT 8192
#define N_TOT 4096
#define K_TOT 4096
#define BM 128
#define BN 128
#define BK 64

#define XCLAMP 6.0f

typedef int i32x4 __attribute__((ext_vector_type(4)));

__device__ __forceinline__ int q8(float v, float r) {
    float c = fminf(fmaxf(v * r, -127.0f), 127.0f);
    return (int)rintf(c);
}

// Fused converts: threads [0, nx4) quantize x (fp32->i8), [nx4, nx4+nw4)
// truncate w (i32->i8). 16B coalesced loads, 4B stores.
__global__ __launch_bounds__(256) void cvt_fused(
    const float4* __restrict__ x, const int4* __restrict__ w,
    unsigned* __restrict__ xq, unsigned* __restrict__ wq, int nx4, int nw4) {
    int i = blockIdx.x * blockDim.x + threadIdx.x;
    if (i < nx4) {
        const float r = 127.0f / XCLAMP;
        float4 v = x[i];
        xq[i] = (unsigned)(q8(v.x, r) & 0xff)
              | ((unsigned)(q8(v.y, r) & 0xff) << 8)
              | ((unsigned)(q8(v.z, r) & 0xff) << 16)
              | ((unsigned)(q8(v.w, r) & 0xff) << 24);
    } else {
        int j = i - nx4;
        if (j >= nw4) return;
        int4 a = w[j];
        wq[j] = (unsigned)(a.x & 0xff)
              | ((unsigned)(a.y & 0xff) << 8)
              | ((unsigned)(a.z & 0xff) << 16)
              | ((unsigned)(a.w & 0xff) << 24);
    }
}

#define GLOAD_LDS16(gptr, lptr)                                                  \
    __builtin_amdgcn_global_load_lds(                                            \
        (const __attribute__((address_space(1))) void*)(gptr),                   \
        (__attribute__((address_space(3))) void*)(lptr), 16, 0, 0)

// C = A(MxK,i8) * B(NxK,i8)^T, epilogue: out = (s_x*s_w)*acc_i32 + bias[n]
__global__ __launch_bounds__(256) void gemm_i8(
    const signed char* __restrict__ A, const signed char* __restrict__ B,
    const float* __restrict__ scale, const float* __restrict__ bias,
    float* __restrict__ out) {
    // LDS tile [128][64] B, NO padding. Chunk swizzle: LDS(row r, pos p)
    // holds global chunk c = p ^ ((r>>1)&3)  (16B chunks, 4 per row).
    __shared__ alignas(16) signed char As[BM * BK];
    __shared__ alignas(16) signed char Bs[BN * BK];

    const int tid  = threadIdx.x;
    const int wave = tid >> 6;
    const int lane = tid & 63;
    const int bm = blockIdx.x;       // 0..63
    const int bn = blockIdx.y;       // 0..31
    const int wm = (wave >> 1) * 64;
    const int wn = (wave & 1) * 64;

    i32x4 acc[4][4] = {};

    const char* Ag = (const char*)A + (size_t)bm * BM * K_TOT;
    const char* Bg = (const char*)B + (size_t)bn * BN * K_TOT;
    char* AsW = (char*)As + wave * 1024;
    char* BsW = (char*)Bs + wave * 1024;

    // staging: lane's fixed LDS slot f -> (row, pos); fetch global chunk pos^swz(row)
    const int f0 = tid * 16;
    const int f1 = f0 + 4096;
    const int r0 = f0 >> 6, c0 = (((f0 >> 4) & 3) ^ ((r0 >> 1) & 3)) * 16;
    const int r1 = f1 >> 6, c1 = (((f1 >> 4) & 3) ^ ((r1 >> 1) & 3)) * 16;

    // fragment read: row R = wm+i*16+frow, chunk g=lane>>4 is at LDS pos
    // g ^ ((R>>1)&3); since (wm+i*16)>>1 is 0 mod 4, swz = (frow>>1)&3.
    const int frow = lane & 15;
    const int fkb  = (((lane >> 4) ^ ((frow >> 1) & 3)) * 16);

    for (int k0 = 0; k0 < K_TOT; k0 += BK) {
        const char* ka = Ag + k0;
        const char* kb = Bg + k0;
        GLOAD_LDS16(ka + (size_t)r0 * K_TOT + c0, AsW);
        GLOAD_LDS16(ka + (size_t)r1 * K_TOT + c1, AsW + 4096);
        GLOAD_LDS16(kb + (size_t)r0 * K_TOT + c0, BsW);
        GLOAD_LDS16(kb + (size_t)r1 * K_TOT + c1, BsW + 4096);
        __syncthreads();

        i32x4 af[4], bf[4];
#pragma unroll
        for (int i = 0; i < 4; i++)
            af[i] = *(const i32x4*)(As + (wm + i * 16 + frow) * BK + fkb);
#pragma unroll
        for (int j = 0; j < 4; j++)
            bf[j] = *(const i32x4*)(Bs + (wn + j * 16 + frow) * BK + fkb);

#pragma unroll
        for (int i = 0; i < 4; i++)
#pragma unroll
            for (int j = 0; j < 4; j++)
                acc[i][j] = __builtin_amdgcn_mfma_i32_16x16x64_i8(
                    af[i], bf[j], acc[i][j], 0, 0, 0);
        __syncthreads();
    }

    // epilogue: C/D layout col=lane&15, row=(lane>>4)*4+reg (dtype-independent)
    const float s = scale[0] * (XCLAMP / 127.0f);
    const int colq = lane & 15;
    const int rowq = (lane >> 4) * 4;
#pragma unroll
    for (int i = 0; i < 4; i++) {
        const int rbase = bm * BM + wm + i * 16 + rowq;
#pragma unroll
        for (int j = 0; j < 4; j++) {
            const int c = bn * BN + wn + j * 16 + colq;
            const float bv = bias[c];
#pragma unroll
            for (int r = 0; r < 4; r++)
                out[(size_t)(rbase + r) * N_TOT + c] = s * (float)acc[i][j][r] + bv;
        }
    }
}

extern "C" void kernel_launch(void* const* d_in, const int* in_sizes, int n_in,
                              void* d_out, int out_size, void* d_ws, size_t ws_size,
                              hipStream_t stream) {
    const float* x     = (const float*)d_in[0];   // [8192, 4096] fp32
    const int*   w     = (const int*)d_in[1];     // [4096, 4096] int32
    const float* scale = (const float*)d_in[2];   // [1]
    const float* bias  = (const float*)d_in[3];   // [4096]
    float* out = (float*)d_out;

    signed char* Xq = (signed char*)d_ws;                           // 32 MiB
    signed char* Wq = (signed char*)d_ws + (size_t)M_TOT * K_TOT;   // +16 MiB

    const int nx4 = M_TOT * K_TOT / 4;  // 8388608
    const int nw4 = N_TOT * K_TOT / 4;  // 4194304
    const int ncvt = nx4 + nw4;
    cvt_fused<<<(ncvt + 255) / 256, 256, 0, stream>>>(
        (const float4*)x, (const int4*)w, (unsigned*)Xq, (unsigned*)Wq, nx4, nw4);

    dim3 grid(M_TOT / BM, N_TOT / BN);  // 64 x 32
    gemm_i8<<<grid, 256, 0, stream>>>(Xq, Wq, scale, bias, out);
}

// Round 4
// 413.539 us; speedup vs baseline: 1.0146x; 1.0146x over previous
//
#include <hip/hip_runtime.h>
#include <stdint.h>

// ---------------------------------------------------------------------------
// QuantizedLinear via int8 MFMA: y[m,n] = s_x*s_w * (xq @ wq^T)[m,n] + bias[n]
// W int8 exact; x quantized at 6/127 (clamp +-6). int32 accum exact.
// R4: BK=128 (i8) -> 32 K-iterations (was 64), 32 MFMA/wave per barrier
//     (AITER density, s02). LDS 32 KB/block -> still 5 blocks/CU (avoids
//     m132's bf16 occupancy collapse). XOR chunk swizzle rebuilt for the
//     8-chunk row: LDS(r,p) holds global chunk p^(r&7); row stride 128 B
//     = 32 banks exactly, so unswizzled reads would be 16-way conflicted.
// ---------------------------------------------------------------------------

#define M_TOT 8192
#define N_TOT 4096
#define K_TOT 4096
#define BM 128
#define BN 128
#define BK 128   // i8 elements = 128 B per tile row = 8 x 16B chunks

#define XCLAMP 6.0f

typedef int i32x4 __attribute__((ext_vector_type(4)));

__device__ __forceinline__ int q8(float v, float r) {
    float c = fminf(fmaxf(v * r, -127.0f), 127.0f);
    return (int)rintf(c);
}

// Fused converts: threads [0, nx4) quantize x (fp32->i8), [nx4, nx4+nw4)
// truncate w (i32->i8). 16B coalesced loads, 4B stores.
__global__ __launch_bounds__(256) void cvt_fused(
    const float4* __restrict__ x, const int4* __restrict__ w,
    unsigned* __restrict__ xq, unsigned* __restrict__ wq, int nx4, int nw4) {
    int i = blockIdx.x * blockDim.x + threadIdx.x;
    if (i < nx4) {
        const float r = 127.0f / XCLAMP;
        float4 v = x[i];
        xq[i] = (unsigned)(q8(v.x, r) & 0xff)
              | ((unsigned)(q8(v.y, r) & 0xff) << 8)
              | ((unsigned)(q8(v.z, r) & 0xff) << 16)
              | ((unsigned)(q8(v.w, r) & 0xff) << 24);
    } else {
        int j = i - nx4;
        if (j >= nw4) return;
        int4 a = w[j];
        wq[j] = (unsigned)(a.x & 0xff)
              | ((unsigned)(a.y & 0xff) << 8)
              | ((unsigned)(a.z & 0xff) << 16)
              | ((unsigned)(a.w & 0xff) << 24);
    }
}

#define GLOAD_LDS16(gptr, lptr)                                                  \
    __builtin_amdgcn_global_load_lds(                                            \
        (const __attribute__((address_space(1))) void*)(gptr),                   \
        (__attribute__((address_space(3))) void*)(lptr), 16, 0, 0)

// C = A(MxK,i8) * B(NxK,i8)^T, epilogue: out = (s_x*s_w)*acc_i32 + bias[n]
__global__ __launch_bounds__(256) void gemm_i8(
    const signed char* __restrict__ A, const signed char* __restrict__ B,
    const float* __restrict__ scale, const float* __restrict__ bias,
    float* __restrict__ out) {
    // LDS tile [128 rows][128 B], NO padding (global_load_lds order fixed).
    // Chunk swizzle: LDS(row r, pos p) holds global 16B-chunk c = p ^ (r&7).
    __shared__ alignas(16) signed char As[BM * BK];  // 16 KB
    __shared__ alignas(16) signed char Bs[BN * BK];  // 16 KB

    const int tid  = threadIdx.x;
    const int wave = tid >> 6;
    const int lane = tid & 63;
    const int bm = blockIdx.x;       // 0..63
    const int bn = blockIdx.y;       // 0..31
    const int wm = (wave >> 1) * 64;
    const int wn = (wave & 1) * 64;

    i32x4 acc[4][4] = {};

    const char* Ag = (const char*)A + (size_t)bm * BM * K_TOT;
    const char* Bg = (const char*)B + (size_t)bn * BN * K_TOT;

    // staging: 4 passes of 4 KB per matrix; lane slot f = tid*16 + pass*4096.
    // LDS dest (wave-uniform + lane*16): base + pass*4096 + wave*1024.
    // Global source for slot (r = f>>7, p = (f>>4)&7): row r, col (p^(r&7))*16.
    int srow[4], scol[4];
#pragma unroll
    for (int ps = 0; ps < 4; ps++) {
        const int f = tid * 16 + ps * 4096;
        const int r = f >> 7, p = (f >> 4) & 7;
        srow[ps] = r;
        scol[ps] = ((p ^ (r & 7)) << 4);
    }
    char* AsW = (char*)As + wave * 1024;
    char* BsW = (char*)Bs + wave * 1024;

    // fragment read coords: row R = wm|wn + i*16 + frow (R&7 == frow&7);
    // k-step s chunk g = (lane>>4) + 4*s sits at LDS pos g ^ (frow&7).
    const int frow = lane & 15;
    const int pos0 = (((lane >> 4) + 0) ^ (frow & 7)) << 4;   // s=0
    const int pos1 = (((lane >> 4) + 4) ^ (frow & 7)) << 4;   // s=1

    for (int k0 = 0; k0 < K_TOT; k0 += BK) {
        const char* ka = Ag + k0;
        const char* kb = Bg + k0;
#pragma unroll
        for (int ps = 0; ps < 4; ps++) {
            GLOAD_LDS16(ka + (size_t)srow[ps] * K_TOT + scol[ps], AsW + ps * 4096);
            GLOAD_LDS16(kb + (size_t)srow[ps] * K_TOT + scol[ps], BsW + ps * 4096);
        }
        __syncthreads();

        i32x4 af0[4], bf0[4], af1[4], bf1[4];
#pragma unroll
        for (int i = 0; i < 4; i++) {
            const int rb = (wm + i * 16 + frow) * BK;
            af0[i] = *(const i32x4*)(As + rb + pos0);
            af1[i] = *(const i32x4*)(As + rb + pos1);
        }
#pragma unroll
        for (int j = 0; j < 4; j++) {
            const int rb = (wn + j * 16 + frow) * BK;
            bf0[j] = *(const i32x4*)(Bs + rb + pos0);
            bf1[j] = *(const i32x4*)(Bs + rb + pos1);
        }

#pragma unroll
        for (int i = 0; i < 4; i++)
#pragma unroll
            for (int j = 0; j < 4; j++)
                acc[i][j] = __builtin_amdgcn_mfma_i32_16x16x64_i8(
                    af0[i], bf0[j], acc[i][j], 0, 0, 0);
#pragma unroll
        for (int i = 0; i < 4; i++)
#pragma unroll
            for (int j = 0; j < 4; j++)
                acc[i][j] = __builtin_amdgcn_mfma_i32_16x16x64_i8(
                    af1[i], bf1[j], acc[i][j], 0, 0, 0);
        __syncthreads();
    }

    // epilogue: C/D layout col=lane&15, row=(lane>>4)*4+reg (dtype-independent)
    const float s = scale[0] * (XCLAMP / 127.0f);
    const int colq = lane & 15;
    const int rowq = (lane >> 4) * 4;
#pragma unroll
    for (int i = 0; i < 4; i++) {
        const int rbase = bm * BM + wm + i * 16 + rowq;
#pragma unroll
        for (int j = 0; j < 4; j++) {
            const int c = bn * BN + wn + j * 16 + colq;
            const float bv = bias[c];
#pragma unroll
            for (int r = 0; r < 4; r++)
                out[(size_t)(rbase + r) * N_TOT + c] = s * (float)acc[i][j][r] + bv;
        }
    }
}

extern "C" void kernel_launch(void* const* d_in, const int* in_sizes, int n_in,
                              void* d_out, int out_size, void* d_ws, size_t ws_size,
                              hipStream_t stream) {
    const float* x     = (const float*)d_in[0];   // [8192, 4096] fp32
    const int*   w     = (const int*)d_in[1];     // [4096, 4096] int32
    const float* scale = (const float*)d_in[2];   // [1]
    const float* bias  = (const float*)d_in[3];   // [4096]
    float* out = (float*)d_out;

    signed char* Xq = (signed char*)d_ws;                           // 32 MiB
    signed char* Wq = (signed char*)d_ws + (size_t)M_TOT * K_TOT;   // +16 MiB

    const int nx4 = M_TOT * K_TOT / 4;  // 8388608
    const int nw4 = N_TOT * K_TOT / 4;  // 4194304
    const int ncvt = nx4 + nw4;
    cvt_fused<<<(ncvt + 255) / 256, 256, 0, stream>>>(
        (const float4*)x, (const int4*)w, (unsigned*)Xq, (unsigned*)Wq, nx4, nw4);

    dim3 grid(M_TOT / BM, N_TOT / BN);  // 64 x 32
    gemm_i8<<<grid, 256, 0, stream>>>(Xq, Wq, scale, bias, out);
}